// Round 6
// baseline (379.623 us; speedup 1.0000x reference)
//
#include <hip/hip_runtime.h>

// WKV scan, B=8, S=2048, E=2048, fp32 — chunked 3-pass scan, float4 channels.
//
// R3 post-mortem: pass1 (scalar loads, 15 waves/CU) ran 103.9us at only
// 2.4 TB/s effective with VALUBusy 13% and plenty of bytes in flight ->
// not latency-bound, suspected 256B-granule DRAM/L3 inefficiency.
// R4: 4 channels/thread (float4 = 1KB/wave/instr), CH=32 chunks,
// 256-thread blocks -> ~8 waves/CU x 16KB in flight each.
// R5: fix nt-store build break (HIP float4 is a class; clang builtin needs a
// native vector) via ext_vector_type(4).
// R6: resubmit (R5 never ran — broker timeout). One variable at a time.

#define B_ 8
#define S_ 2048
#define E_ 2048
constexpr int BE  = B_ * E_;     // 16384 channels
constexpr int CH  = 32;          // chunks
constexpr int CL  = S_ / CH;     // 64 steps per chunk
constexpr int NT4 = BE / 4;      // 4096 vector-threads (4 ch each) = 2^12
constexpr int E4  = E_ / 4;      // 512 float4 per row = 2^9

typedef float f32x4 __attribute__((ext_vector_type(4)));

// ---------------- pass 1: per-chunk summaries from zero state ----------------
__global__ __launch_bounds__(256) void wkv_pass1(
    const float* __restrict__ td_g,
    const float* __restrict__ k_g, const float* __restrict__ v_g,
    float* __restrict__ sa, float* __restrict__ sb, float* __restrict__ se)
{
    const int gid = blockIdx.x * 256 + threadIdx.x;
    const int j  = gid >> 12;          // chunk 0..CH-2
    const int c4 = gid & (NT4 - 1);
    const int b  = c4 >> 9;
    const int e4 = c4 & (E4 - 1);
    const float4 td4 = ((const float4*)td_g)[e4];
    const long base4 = ((long)b * S_ * E_ + (long)(j * CL) * E_) / 4 + e4;
    const float4* __restrict__ kp = (const float4*)k_g + base4;
    const float4* __restrict__ vp = (const float4*)v_g + base4;

    float4 aa = {0,0,0,0}, bb = {0,0,0,0}, eps = {0,0,0,0};
    constexpr int U = 8;
    float4 kA[U], vA[U], kB[U], vB[U];
#pragma unroll
    for (int i = 0; i < U; ++i) { kA[i] = kp[i * E4]; vA[i] = vp[i * E4]; }

#define STEP1(k4, v4, C) { \
    const float tde = td4.C + eps.C; \
    const float m   = fmaxf(tde, (k4).C); \
    const float p   = __expf(tde - m); \
    const float q   = __expf((k4).C - m); \
    aa.C = fmaf(aa.C, p, (v4).C * q); \
    bb.C = fmaf(bb.C, p, q); \
    eps.C = m; }
#define STEP1ALL(k4, v4) { STEP1(k4,v4,x) STEP1(k4,v4,y) STEP1(k4,v4,z) STEP1(k4,v4,w) }

    for (int t0 = 0; t0 < CL; t0 += 2 * U) {
#pragma unroll
        for (int i = 0; i < U; ++i) { kB[i] = kp[(t0+U+i) * E4]; vB[i] = vp[(t0+U+i) * E4]; }
#pragma unroll
        for (int i = 0; i < U; ++i) STEP1ALL(kA[i], vA[i]);
        if (t0 + 2 * U < CL) {
#pragma unroll
            for (int i = 0; i < U; ++i) { kA[i] = kp[(t0+2*U+i) * E4]; vA[i] = vp[(t0+2*U+i) * E4]; }
        }
#pragma unroll
        for (int i = 0; i < U; ++i) STEP1ALL(kB[i], vB[i]);
    }
    ((float4*)sa)[j * NT4 + c4] = aa;
    ((float4*)sb)[j * NT4 + c4] = bb;
    ((float4*)se)[j * NT4 + c4] = eps;
}

// ---------------- pass 2: fold summaries -> per-chunk incoming states --------
__global__ __launch_bounds__(256) void wkv_pass2(
    const float* __restrict__ td_g,
    const float* __restrict__ sa, const float* __restrict__ sb, const float* __restrict__ se,
    float* __restrict__ ia, float* __restrict__ ib, float* __restrict__ ie)
{
    const int c = blockIdx.x * 256 + threadIdx.x;   // 0..BE-1
    const int e = c & (E_ - 1);
    const float Ltd = (float)CL * td_g[e];

    float aa = 0.f, bb = 0.f, eps = 0.f;
    ia[c] = 0.f; ib[c] = 0.f; ie[c] = 0.f;          // chunk 0 starts from zero
#pragma unroll
    for (int j = 1; j < CH; ++j) {
        const float a_c = sa[(j - 1) * BE + c];
        const float b_c = sb[(j - 1) * BE + c];
        const float e_c = se[(j - 1) * BE + c];
        const float ed  = eps + Ltd;
        const float ne  = fmaxf(ed, e_c);
        const float f1  = __expf(ed - ne);
        const float f2  = __expf(e_c - ne);
        aa = aa * f1 + a_c * f2;
        bb = bb * f1 + b_c * f2;
        eps = ne;
        ia[j * BE + c] = aa;
        ib[j * BE + c] = bb;
        ie[j * BE + c] = eps;
    }
}

// ---------------- pass 3: replay each chunk with true incoming state ---------
__global__ __launch_bounds__(256) void wkv_pass3(
    const float* __restrict__ td_g, const float* __restrict__ tf_g,
    const float* __restrict__ k_g, const float* __restrict__ v_g,
    const float* __restrict__ ia, const float* __restrict__ ib, const float* __restrict__ ie,
    float* __restrict__ y_g)
{
    const int gid = blockIdx.x * 256 + threadIdx.x;
    const int j  = gid >> 12;          // chunk 0..CH-1
    const int c4 = gid & (NT4 - 1);
    const int b  = c4 >> 9;
    const int e4 = c4 & (E4 - 1);
    const float4 td4 = ((const float4*)td_g)[e4];
    const float4 tf4 = ((const float4*)tf_g)[e4];
    const long base4 = ((long)b * S_ * E_ + (long)(j * CL) * E_) / 4 + e4;
    const float4* __restrict__ kp = (const float4*)k_g + base4;
    const float4* __restrict__ vp = (const float4*)v_g + base4;
    f32x4* __restrict__ yp = (f32x4*)y_g + base4;

    float4 aa  = ((const float4*)ia)[j * NT4 + c4];
    float4 bb  = ((const float4*)ib)[j * NT4 + c4];
    float4 eps = ((const float4*)ie)[j * NT4 + c4];

    constexpr int U = 8;
    float4 kA[U], vA[U], kB[U], vB[U];
#pragma unroll
    for (int i = 0; i < U; ++i) { kA[i] = kp[i * E4]; vA[i] = vp[i * E4]; }

#define STEP3(k4, v4, C, YI) { \
    const float e1 = __expf(tf4.C + (k4).C - eps.C); \
    y4[YI] = __fdividef(fmaf((v4).C, e1, aa.C), bb.C + e1); \
    const float tde = td4.C + eps.C; \
    const float m   = fmaxf(tde, (k4).C); \
    const float p   = __expf(tde - m); \
    const float q   = __expf((k4).C - m); \
    aa.C = fmaf(aa.C, p, (v4).C * q); \
    bb.C = fmaf(bb.C, p, q); \
    eps.C = m; }
#define STEP3ALL(k4, v4, t) { f32x4 y4; \
    STEP3(k4,v4,x,0) STEP3(k4,v4,y,1) STEP3(k4,v4,z,2) STEP3(k4,v4,w,3) \
    __builtin_nontemporal_store(y4, &yp[(t) * E4]); }

    for (int t0 = 0; t0 < CL; t0 += 2 * U) {
#pragma unroll
        for (int i = 0; i < U; ++i) { kB[i] = kp[(t0+U+i) * E4]; vB[i] = vp[(t0+U+i) * E4]; }
#pragma unroll
        for (int i = 0; i < U; ++i) STEP3ALL(kA[i], vA[i], t0 + i);
        if (t0 + 2 * U < CL) {
#pragma unroll
            for (int i = 0; i < U; ++i) { kA[i] = kp[(t0+2*U+i) * E4]; vA[i] = vp[(t0+2*U+i) * E4]; }
        }
#pragma unroll
        for (int i = 0; i < U; ++i) STEP3ALL(kB[i], vB[i], t0 + U + i);
    }
}

// ---------------- fallback: single-pass kernel (if ws too small) -------------
__global__ __launch_bounds__(64) void wkv_single(
    const float* __restrict__ td_g, const float* __restrict__ tf_g,
    const float* __restrict__ k_g, const float* __restrict__ v_g,
    float* __restrict__ y_g)
{
    const int c = blockIdx.x * 64 + threadIdx.x;
    const int b = c >> 11;
    const int e = c & (E_ - 1);
    const float td = td_g[e];
    const float tf = tf_g[e];
    const long base = (long)b * S_ * E_ + e;
    const float* __restrict__ kp = k_g + base;
    const float* __restrict__ vp = v_g + base;
    float* __restrict__ yp = y_g + base;
    float aa = 0.f, bb = 0.f, eps = 0.f;
    for (int t = 0; t < S_; ++t) {
        const float kt = kp[t * E_], vt = vp[t * E_];
        const float e1 = __expf(tf + kt - eps);
        yp[t * E_] = __fdividef(fmaf(vt, e1, aa), bb + e1);
        const float tde = td + eps;
        const float m = fmaxf(tde, kt);
        const float p = __expf(tde - m);
        const float q = __expf(kt - m);
        aa = fmaf(aa, p, vt * q);
        bb = fmaf(bb, p, q);
        eps = m;
    }
}

extern "C" void kernel_launch(void* const* d_in, const int* in_sizes, int n_in,
                              void* d_out, int out_size, void* d_ws, size_t ws_size,
                              hipStream_t stream) {
    // setup_inputs order: batch_size, seq_len, embedding_dim,
    //                     time_decay, time_first, k, v
    const float* td = (const float*)d_in[3];
    const float* tf = (const float*)d_in[4];
    const float* k  = (const float*)d_in[5];
    const float* v  = (const float*)d_in[6];
    float* y        = (float*)d_out;
    (void)in_sizes; (void)n_in; (void)out_size;

    const size_t arr = (size_t)CH * BE * sizeof(float);   // 2 MiB per array
    if (ws_size < 6 * arr) {
        hipLaunchKernelGGL(wkv_single, dim3(BE / 64), dim3(64), 0, stream, td, tf, k, v, y);
        return;
    }
    float* sa = (float*)d_ws;
    float* sb = sa + CH * BE;
    float* se = sb + CH * BE;
    float* ia = se + CH * BE;
    float* ib = ia + CH * BE;
    float* ie = ib + CH * BE;

    hipLaunchKernelGGL(wkv_pass1, dim3((CH - 1) * NT4 / 256), dim3(256), 0, stream,
                       td, k, v, sa, sb, se);
    hipLaunchKernelGGL(wkv_pass2, dim3(BE / 256), dim3(256), 0, stream,
                       td, sa, sb, se, ia, ib, ie);
    hipLaunchKernelGGL(wkv_pass3, dim3(CH * NT4 / 256), dim3(256), 0, stream,
                       td, tf, k, v, ia, ib, ie, y);
}